// Round 5
// baseline (94.656 us; speedup 1.0000x reference)
//
#include <hip/hip_runtime.h>
#include <stdint.h>

#define N      8192
#define KDIM   256
#define BM     128
#define TILES  (N / BM)                    // 64
#define NPAIRS (TILES * (TILES + 1) / 2)   // 2080
#define MARGIN 0.5f
#define PS     ((size_t)N * 64)            // chunk-plane stride (bytes)

typedef float     f32x4 __attribute__((ext_vector_type(4)));
typedef long long i64x2 __attribute__((ext_vector_type(2)));

// async global->LDS, 16 B/lane; LDS dest = wave-uniform base + lane*16
__device__ __forceinline__ void async_copy16(const void* g, void* l) {
    __builtin_amdgcn_global_load_lds(
        (__attribute__((address_space(1))) void*)(g),
        (__attribute__((address_space(3))) void*)(l),
        16, 0, 0);
}

#if !__has_builtin(__builtin_amdgcn_cvt_pk_fp8_f32)
__device__ __forceinline__ uint32_t f2e4m3(float f) {
    uint32_t u = __float_as_uint(f);
    uint32_t s = (u >> 24) & 0x80u;
    uint32_t au = u & 0x7fffffffu;
    if (au == 0) return s;
    int32_t  exp = (int32_t)(au >> 23) - 127;
    uint32_t man = (au & 0x7fffffu) | 0x800000u;
    uint32_t code;
    if (exp >= -6) {
        code = (uint32_t)((exp + 7) << 3) | ((man >> 20) & 7u);
        uint32_t rem = man & 0xFFFFFu;
        if (rem > 0x80000u || (rem == 0x80000u && (code & 1u))) code++;
    } else {
        int shift = 14 - exp;
        if (shift > 24) return s;
        code = man >> shift;
        uint32_t rem = man & ((1u << shift) - 1u);
        uint32_t h = 1u << (shift - 1);
        if (rem > h || (rem == h && (code & 1u))) code++;
    }
    return s | code;
}
__device__ __forceinline__ uint32_t pack_fp8x4(float4 v) {
    return f2e4m3(v.x) | (f2e4m3(v.y) << 8) | (f2e4m3(v.z) << 16) |
           (f2e4m3(v.w) << 24);
}
#else
__device__ __forceinline__ uint32_t pack_fp8x4(float4 v) {
    int pk = __builtin_amdgcn_cvt_pk_fp8_f32(v.x, v.y, 0, false);
    pk = __builtin_amdgcn_cvt_pk_fp8_f32(v.z, v.w, pk, true);
    return (uint32_t)pk;
}
#endif

// ---------------------------------------------------------------------------
// Prepass: fp32 -> fp8 e4m3 into 4 chunk-planes (plane c = k in [64c,64c+64),
// row-major 64 B/row) so the loss kernel stages each 128x64 chunk as ONE
// contiguous 8 KB block. Exact fp32 row norms. Also zeroes the output
// accumulator (loss kernel atomically adds into it).
// ---------------------------------------------------------------------------
__global__ __launch_bounds__(256) void prep_kernel(
        const float* __restrict__ X, uint8_t* __restrict__ Xq,
        float* __restrict__ sq, float* __restrict__ out) {
    int row  = blockIdx.x * 4 + (threadIdx.x >> 6);
    int lane = threadIdx.x & 63;

    float4 v = *((const float4*)(X + (size_t)row * KDIM) + lane);
    float ss = v.x * v.x + v.y * v.y + v.z * v.z + v.w * v.w;
    uint32_t pk = pack_fp8x4(v);

    int c = lane >> 4;                 // chunk plane (k = 4*lane)
    int p = (lane * 4) & 63;           // byte within 64 B chunk-row
    *(uint32_t*)(Xq + (size_t)c * PS + (size_t)row * 64 + p) = pk;

    #pragma unroll
    for (int o = 32; o > 0; o >>= 1) ss += __shfl_down(ss, o, 64);
    if (lane == 0) sq[row] = ss;
    if (blockIdx.x == 0 && threadIdx.x == 0) out[0] = 0.0f;
}

// ---------------------------------------------------------------------------
// Main: triangular grid of 128x128 Gram tiles, fp8 16x16x32 MFMA.
// Software-pipelined K-loop: 4 chunks of K=64, ping-pong LDS buffers
// (2x(8+8) KB = 32 KB -> 4 blocks/CU); chunk c+1's global_load_lds is issued
// BEFORE computing chunk c, so the barrier drain finds loads complete.
// Fused contrastive-loss epilogue + device-scope atomic accumulate.
// ---------------------------------------------------------------------------
__global__ __launch_bounds__(256, 4) void loss_kernel(
        const uint8_t* __restrict__ Xq, const float* __restrict__ sq,
        const int* __restrict__ tgt, float* __restrict__ out) {
    // ---- triangular decode: p -> (bi, bj), bi <= bj ----
    const int p = blockIdx.x;
    float tf = 2.0f * TILES + 1.0f;
    int bi = (int)((tf - sqrtf(tf * tf - 8.0f * (float)p)) * 0.5f);
    if (bi < 0) bi = 0;
    while (bi > 0 && (bi * TILES - bi * (bi - 1) / 2) > p) --bi;
    while (((bi + 1) * TILES - (bi + 1) * bi / 2) <= p) ++bi;
    const int bj = bi + (p - (bi * TILES - bi * (bi - 1) / 2));

    __shared__ __align__(16) uint8_t As[2][BM * 64];   // 2 x 8 KB
    __shared__ __align__(16) uint8_t Bs[2][BM * 64];   // 2 x 8 KB
    __shared__ float sqa_s[BM], sqb_s[BM];
    __shared__ int   ta_s[BM],  tb_s[BM];
    __shared__ float wsum[4];

    const int tid  = threadIdx.x;
    const int wave = tid >> 6;
    const int lane = tid & 63;

    if (tid < 128) {
        sqa_s[tid] = sq[bi * BM + tid];
        ta_s[tid]  = tgt[bi * BM + tid];
    } else {
        int r = tid - 128;
        sqb_s[r] = sq[bj * BM + r];
        tb_s[r]  = tgt[bj * BM + r];
    }

    // staging pointers: per-wave 32 rows (2 KB = 2 instrs) of each tile
    const uint8_t* gA = Xq + ((size_t)bi * BM + wave * 32) * 64 + lane * 16;
    const uint8_t* gB = Xq + ((size_t)bj * BM + wave * 32) * 64 + lane * 16;
    uint8_t* lA0 = &As[0][wave * 2048];
    uint8_t* lA1 = &As[1][wave * 2048];
    uint8_t* lB0 = &Bs[0][wave * 2048];
    uint8_t* lB1 = &Bs[1][wave * 2048];

    const int frow  = lane & 15;
    const int fquad = lane >> 4;
    const int wm = (wave >> 1) * 64;
    const int wn = (wave & 1) * 64;

    const uint8_t* aB0 = &As[0][(wm + frow) * 64 + fquad * 16];
    const uint8_t* bB0 = &Bs[0][(wn + frow) * 64 + fquad * 16];
    const uint8_t* aB1 = &As[1][(wm + frow) * 64 + fquad * 16];
    const uint8_t* bB1 = &Bs[1][(wn + frow) * 64 + fquad * 16];

    f32x4 acc[4][4];
    #pragma unroll
    for (int im = 0; im < 4; ++im)
        #pragma unroll
        for (int in = 0; in < 4; ++in)
            acc[im][in] = (f32x4){0.f, 0.f, 0.f, 0.f};

    #define STAGE(c, la, lb)                                                 \
        do {                                                                 \
            async_copy16(gA + (size_t)(c) * PS,        (la));                \
            async_copy16(gA + (size_t)(c) * PS + 1024, (la) + 1024);         \
            async_copy16(gB + (size_t)(c) * PS,        (lb));                \
            async_copy16(gB + (size_t)(c) * PS + 1024, (lb) + 1024);         \
        } while (0)

    #define COMPUTE(ab, bb)                                                  \
        do {                                                                 \
            i64x2 a2[4], b2[4];                                              \
            _Pragma("unroll")                                                \
            for (int im = 0; im < 4; ++im)                                   \
                a2[im] = *(const i64x2*)((ab) + im * 16 * 64);               \
            _Pragma("unroll")                                                \
            for (int in = 0; in < 4; ++in)                                   \
                b2[in] = *(const i64x2*)((bb) + in * 16 * 64);               \
            _Pragma("unroll")                                                \
            for (int im = 0; im < 4; ++im)                                   \
                _Pragma("unroll")                                            \
                for (int in = 0; in < 4; ++in)                               \
                    acc[im][in] = __builtin_amdgcn_mfma_f32_16x16x32_fp8_fp8(\
                        a2[im].x, b2[in].x, acc[im][in], 0, 0, 0);           \
            _Pragma("unroll")                                                \
            for (int im = 0; im < 4; ++im)                                   \
                _Pragma("unroll")                                            \
                for (int in = 0; in < 4; ++in)                               \
                    acc[im][in] = __builtin_amdgcn_mfma_f32_16x16x32_fp8_fp8(\
                        a2[im].y, b2[in].y, acc[im][in], 0, 0, 0);           \
        } while (0)

    STAGE(0, lA0, lB0);
    __syncthreads();
    STAGE(1, lA1, lB1);          // prefetch flies during compute(0)
    COMPUTE(aB0, bB0);
    __syncthreads();
    STAGE(2, lA0, lB0);
    COMPUTE(aB1, bB1);
    __syncthreads();
    STAGE(3, lA1, lB1);
    COMPUTE(aB0, bB0);
    __syncthreads();
    COMPUTE(aB1, bB1);

    #undef STAGE
    #undef COMPUTE

    // ---- epilogue: C/D map col=lane&15, row=(lane>>4)*4+reg ----
    float lsum = 0.0f;
    if (bi != bj) {
        #pragma unroll
        for (int im = 0; im < 4; ++im) {
            #pragma unroll
            for (int in = 0; in < 4; ++in) {
                #pragma unroll
                for (int r = 0; r < 4; ++r) {
                    int rl = wm + im * 16 + fquad * 4 + r;
                    int cl = wn + in * 16 + frow;
                    float d = fmaf(-2.0f, acc[im][in][r],
                                   sqa_s[rl] + sqb_s[cl]);
                    lsum += (ta_s[rl] == tb_s[cl]) ? d
                                                   : fmaxf(MARGIN - d, 0.0f);
                }
            }
        }
        lsum *= 2.0f;   // (i,j) and (j,i)
    } else {
        #pragma unroll
        for (int im = 0; im < 4; ++im) {
            #pragma unroll
            for (int in = 0; in < 4; ++in) {
                #pragma unroll
                for (int r = 0; r < 4; ++r) {
                    int rl = wm + im * 16 + fquad * 4 + r;
                    int cl = wn + in * 16 + frow;
                    float d = fmaf(-2.0f, acc[im][in][r],
                                   sqa_s[rl] + sqb_s[cl]);
                    float c = (ta_s[rl] == tb_s[cl]) ? d
                                                     : fmaxf(MARGIN - d, 0.0f);
                    float w = (rl < cl) ? 2.0f : ((rl == cl) ? 1.0f : 0.0f);
                    lsum += w * c;
                }
            }
        }
    }

    #pragma unroll
    for (int o = 32; o > 0; o >>= 1) lsum += __shfl_down(lsum, o, 64);
    if (lane == 0) wsum[wave] = lsum;
    __syncthreads();
    if (tid == 0) {
        const float scale =
            (float)(1.0 / ((double)N * ((double)N - 1.0) * 2.0));
        atomicAdd(out, (wsum[0] + wsum[1] + wsum[2] + wsum[3]) * scale);
    }
}

extern "C" void kernel_launch(void* const* d_in, const int* in_sizes, int n_in,
                              void* d_out, int out_size, void* d_ws, size_t ws_size,
                              hipStream_t stream) {
    (void)in_sizes; (void)n_in; (void)out_size; (void)ws_size;
    const float* X   = (const float*)d_in[0];
    const int*   tgt = (const int*)d_in[1];

    uint8_t* Xq = (uint8_t*)d_ws;                                  // 2 MB fp8
    float*   sq = (float*)((char*)d_ws + (size_t)N * KDIM);

    prep_kernel<<<N / 4, 256, 0, stream>>>(X, Xq, sq, (float*)d_out);
    loss_kernel<<<NPAIRS, 256, 0, stream>>>(Xq, sq, tgt, (float*)d_out);
}

// Round 6
// 81.513 us; speedup vs baseline: 1.1612x; 1.1612x over previous
//
#include <hip/hip_runtime.h>
#include <stdint.h>

#define N      8192
#define KDIM   256
#define BM     128
#define TILES  (N / BM)                    // 64
#define NPAIRS (TILES * (TILES + 1) / 2)   // 2080
#define MARGIN 0.5f
#define SCALE1 0x7f7f7f7f                  // E8M0 1.0 in every byte

typedef float f32x4 __attribute__((ext_vector_type(4)));
typedef int   i32x4 __attribute__((ext_vector_type(4)));
typedef int   i32x8 __attribute__((ext_vector_type(8)));

// async global->LDS, 16 B/lane; LDS dest = wave-uniform base + lane*16
__device__ __forceinline__ void async_copy16(const void* g, void* l) {
    __builtin_amdgcn_global_load_lds(
        (__attribute__((address_space(1))) void*)(g),
        (__attribute__((address_space(3))) void*)(l),
        16, 0, 0);
}

#if !__has_builtin(__builtin_amdgcn_cvt_pk_fp8_f32)
__device__ __forceinline__ uint32_t f2e4m3(float f) {
    uint32_t u = __float_as_uint(f);
    uint32_t s = (u >> 24) & 0x80u;
    uint32_t au = u & 0x7fffffffu;
    if (au == 0) return s;
    int32_t  exp = (int32_t)(au >> 23) - 127;
    uint32_t man = (au & 0x7fffffu) | 0x800000u;
    uint32_t code;
    if (exp >= -6) {
        code = (uint32_t)((exp + 7) << 3) | ((man >> 20) & 7u);
        uint32_t rem = man & 0xFFFFFu;
        if (rem > 0x80000u || (rem == 0x80000u && (code & 1u))) code++;
    } else {
        int shift = 14 - exp;
        if (shift > 24) return s;
        code = man >> shift;
        uint32_t rem = man & ((1u << shift) - 1u);
        uint32_t h = 1u << (shift - 1);
        if (rem > h || (rem == h && (code & 1u))) code++;
    }
    return s | code;
}
__device__ __forceinline__ uint32_t pack_fp8x4(float4 v) {
    return f2e4m3(v.x) | (f2e4m3(v.y) << 8) | (f2e4m3(v.z) << 16) |
           (f2e4m3(v.w) << 24);
}
#else
__device__ __forceinline__ uint32_t pack_fp8x4(float4 v) {
    int pk = __builtin_amdgcn_cvt_pk_fp8_f32(v.x, v.y, 0, false);
    pk = __builtin_amdgcn_cvt_pk_fp8_f32(v.z, v.w, pk, true);
    return (uint32_t)pk;
}
#endif

// ---------------------------------------------------------------------------
// Prepass: fp32 -> fp8 e4m3, row-major 256 B/row, 16 B granules XOR-swizzled
// by (row&7) within each 128 B half (so loss staging is contiguous per lane
// and its ds_read_b128 is bank-balanced). Exact fp32 row norms.
// ---------------------------------------------------------------------------
__global__ __launch_bounds__(256) void prep_kernel(
        const float* __restrict__ X, uint8_t* __restrict__ Xq,
        float* __restrict__ sq) {
    int row  = blockIdx.x * 4 + (threadIdx.x >> 6);
    int lane = threadIdx.x & 63;

    float4 v = *((const float4*)(X + (size_t)row * KDIM) + lane);
    float ss = v.x * v.x + v.y * v.y + v.z * v.z + v.w * v.w;
    uint32_t pk = pack_fp8x4(v);

    // k = 4*lane: half h, granule g within half, swizzled position
    int h   = lane >> 5;
    int g   = (lane >> 2) & 7;
    int pos = g ^ (row & 7);
    *(uint32_t*)(Xq + (size_t)row * 256 + h * 128 + pos * 16 + (lane & 3) * 4) = pk;

    #pragma unroll
    for (int o = 32; o > 0; o >>= 1) ss += __shfl_down(ss, o, 64);
    if (lane == 0) sq[row] = ss;
}

// ---------------------------------------------------------------------------
// Main: triangular grid of 128x128 Gram tiles. Round-4 skeleton (single
// buffer, BK=128, 3 barriers, 4 blocks/CU) with MX-scaled fp8 MFMA
// (mfma_scale_f32_16x16x128_f8f6f4, unit scales) = 2.3x MFMA rate.
// ---------------------------------------------------------------------------
__global__ __launch_bounds__(256, 4) void loss_kernel(
        const uint8_t* __restrict__ Xq, const float* __restrict__ sq,
        const int* __restrict__ tgt, float* __restrict__ partials) {
    // ---- triangular decode: p -> (bi, bj), bi <= bj ----
    const int p = blockIdx.x;
    float tf = 2.0f * TILES + 1.0f;
    int bi = (int)((tf - sqrtf(tf * tf - 8.0f * (float)p)) * 0.5f);
    if (bi < 0) bi = 0;
    while (bi > 0 && (bi * TILES - bi * (bi - 1) / 2) > p) --bi;
    while (((bi + 1) * TILES - (bi + 1) * bi / 2) <= p) ++bi;
    const int bj = bi + (p - (bi * TILES - bi * (bi - 1) / 2));

    __shared__ __align__(16) uint8_t As[BM * 128];   // 16 KB (one K-half)
    __shared__ __align__(16) uint8_t Bs[BM * 128];   // 16 KB
    __shared__ float sqa_s[BM], sqb_s[BM];
    __shared__ int   ta_s[BM],  tb_s[BM];
    __shared__ float wsum[4];

    const int tid  = threadIdx.x;
    const int wave = tid >> 6;
    const int lane = tid & 63;

    if (tid < 128) {
        sqa_s[tid] = sq[bi * BM + tid];
        ta_s[tid]  = tgt[bi * BM + tid];
    } else {
        int r = tid - 128;
        sqb_s[r] = sq[bj * BM + r];
        tb_s[r]  = tgt[bj * BM + r];
    }

    // staging: 8 rows x 8 granules (16 B) per instruction, 4 per wave per tile
    const int lrow = lane >> 3;
    const int lb   = (lane & 7) * 16;
    const uint8_t* gA = Xq + ((size_t)bi * BM + wave * 32 + lrow) * 256 + lb;
    const uint8_t* gB = Xq + ((size_t)bj * BM + wave * 32 + lrow) * 256 + lb;
    uint8_t* lA = As + wave * 32 * 128;
    uint8_t* lB = Bs + wave * 32 * 128;

    const int frow  = lane & 15;
    const int fquad = lane >> 4;
    const int wm = (wave >> 1) * 64;
    const int wn = (wave & 1) * 64;
    const int key  = frow & 7;
    const int off0 = ((fquad * 2 + 0) ^ key) * 16;
    const int off1 = ((fquad * 2 + 1) ^ key) * 16;
    const uint8_t* aBp = As + (wm + frow) * 128;
    const uint8_t* bBp = Bs + (wn + frow) * 128;

    f32x4 acc[4][4];
    #pragma unroll
    for (int im = 0; im < 4; ++im)
        #pragma unroll
        for (int in = 0; in < 4; ++in)
            acc[im][in] = (f32x4){0.f, 0.f, 0.f, 0.f};

    #pragma unroll
    for (int h = 0; h < 2; ++h) {
        // stage K-half h (A: 16 KB + B: 16 KB across 4 waves)
        #pragma unroll
        for (int q = 0; q < 4; ++q) {
            async_copy16(gA + h * 128 + q * 8 * 256, lA + q * 1024);
            async_copy16(gB + h * 128 + q * 8 * 256, lB + q * 1024);
        }
        __syncthreads();

        i32x8 a8[4];
        #pragma unroll
        for (int im = 0; im < 4; ++im) {
            i32x4 al = *(const i32x4*)(aBp + im * 16 * 128 + off0);
            i32x4 ah = *(const i32x4*)(aBp + im * 16 * 128 + off1);
            a8[im] = __builtin_shufflevector(al, ah, 0, 1, 2, 3, 4, 5, 6, 7);
        }
        #pragma unroll
        for (int in = 0; in < 4; ++in) {
            i32x4 bl = *(const i32x4*)(bBp + in * 16 * 128 + off0);
            i32x4 bh = *(const i32x4*)(bBp + in * 16 * 128 + off1);
            i32x8 b8 = __builtin_shufflevector(bl, bh, 0, 1, 2, 3, 4, 5, 6, 7);
            #pragma unroll
            for (int im = 0; im < 4; ++im)
                acc[im][in] = __builtin_amdgcn_mfma_scale_f32_16x16x128_f8f6f4(
                    a8[im], b8, acc[im][in], 0, 0,    // cbsz=fp8, blgp=fp8
                    0, SCALE1, 0, SCALE1);            // unit scales
        }
        if (h == 0) __syncthreads();   // LDS reuse guard before restaging
    }

    // ---- epilogue: C/D map col=lane&15, row=(lane>>4)*4+reg ----
    float lsum = 0.0f;
    if (bi != bj) {
        #pragma unroll
        for (int im = 0; im < 4; ++im) {
            #pragma unroll
            for (int in = 0; in < 4; ++in) {
                #pragma unroll
                for (int r = 0; r < 4; ++r) {
                    int rl = wm + im * 16 + fquad * 4 + r;
                    int cl = wn + in * 16 + frow;
                    float d = fmaf(-2.0f, acc[im][in][r],
                                   sqa_s[rl] + sqb_s[cl]);
                    lsum += (ta_s[rl] == tb_s[cl]) ? d
                                                   : fmaxf(MARGIN - d, 0.0f);
                }
            }
        }
        lsum *= 2.0f;   // (i,j) and (j,i)
    } else {
        #pragma unroll
        for (int im = 0; im < 4; ++im) {
            #pragma unroll
            for (int in = 0; in < 4; ++in) {
                #pragma unroll
                for (int r = 0; r < 4; ++r) {
                    int rl = wm + im * 16 + fquad * 4 + r;
                    int cl = wn + in * 16 + frow;
                    float d = fmaf(-2.0f, acc[im][in][r],
                                   sqa_s[rl] + sqb_s[cl]);
                    float c = (ta_s[rl] == tb_s[cl]) ? d
                                                     : fmaxf(MARGIN - d, 0.0f);
                    float w = (rl < cl) ? 2.0f : ((rl == cl) ? 1.0f : 0.0f);
                    lsum += w * c;
                }
            }
        }
    }

    #pragma unroll
    for (int o = 32; o > 0; o >>= 1) lsum += __shfl_down(lsum, o, 64);
    if (lane == 0) wsum[wave] = lsum;
    __syncthreads();
    if (tid == 0) partials[p] = wsum[0] + wsum[1] + wsum[2] + wsum[3];
}

// ---------------------------------------------------------------------------
// Final deterministic reduce of NPAIRS partials -> scaled scalar.
// ---------------------------------------------------------------------------
__global__ __launch_bounds__(256) void reduce_kernel(
        const float* __restrict__ partials, float* __restrict__ out,
        int n, float scale) {
    float s = 0.0f;
    for (int i = threadIdx.x; i < n; i += 256) s += partials[i];
    __shared__ float w[4];
    #pragma unroll
    for (int o = 32; o > 0; o >>= 1) s += __shfl_down(s, o, 64);
    int wave = threadIdx.x >> 6, lane = threadIdx.x & 63;
    if (lane == 0) w[wave] = s;
    __syncthreads();
    if (threadIdx.x == 0) out[0] = (w[0] + w[1] + w[2] + w[3]) * scale;
}

extern "C" void kernel_launch(void* const* d_in, const int* in_sizes, int n_in,
                              void* d_out, int out_size, void* d_ws, size_t ws_size,
                              hipStream_t stream) {
    (void)in_sizes; (void)n_in; (void)out_size; (void)ws_size;
    const float* X   = (const float*)d_in[0];
    const int*   tgt = (const int*)d_in[1];

    uint8_t* Xq     = (uint8_t*)d_ws;                              // 2 MB fp8
    float* sq       = (float*)((char*)d_ws + (size_t)N * KDIM);
    float* partials = sq + N;                                      // NPAIRS

    prep_kernel<<<N / 4, 256, 0, stream>>>(X, Xq, sq);
    loss_kernel<<<NPAIRS, 256, 0, stream>>>(Xq, sq, tgt, partials);

    const float scale = (float)(1.0 / ((double)N * ((double)N - 1.0) * 2.0));
    reduce_kernel<<<1, 256, 0, stream>>>(partials, (float*)d_out, NPAIRS, scale);
}